// Round 9
// baseline (2998.814 us; speedup 1.0000x reference)
//
#include <hip/hip_runtime.h>
#include <stdint.h>

#define NN 6000
#define EE 120000
#define DD 128
#define CC 384
#define HDIM 512
#define OUT_NODES (NN*DD)
#define OUT_TOTAL (NN*DD + EE*DD)
#define LS 40   // LDS row stride in u16 (80B = 5x16B: b128-aligned, breaks pow-2 bank aliasing)

typedef unsigned short u16;
typedef __bf16 bf16x8 __attribute__((ext_vector_type(8)));
typedef float f32x4 __attribute__((ext_vector_type(4)));

__device__ __forceinline__ float bf2f(u16 u){ union{unsigned i; float f;} x; x.i=(unsigned)u<<16; return x.f; }
__device__ __forceinline__ u16 f2bf(float f){ union{unsigned i; float f;} x; x.f=f; unsigned r=(x.i + 0x7fffu + ((x.i>>16)&1u))>>16; return (u16)r; }
__device__ __forceinline__ float gelu_f(float v){ return 0.5f*v*(1.f + erff(v*0.70710678118654752f)); }

// epi: 3 = bias->fp32 ; 4 = gelu->fp32 ; 5 = gelu->split pair ; 6 = bias->split pair
__device__ __forceinline__ void epi_std(
    f32x4 acc[4][4], const float* bias, float* Cf, u16* Ch, u16* Cl,
    int M, int ldc, int epi, int m0, int n0, int lane, int wm, int wn)
{
  const int rl = wm*64 + (lane >> 4) * 4;
  const int cl_ = wn*64 + (lane & 15);
#pragma unroll
  for (int ni = 0; ni < 4; ++ni) {
    int gn = n0 + cl_ + ni*16;
    float bvv = bias ? bias[gn] : 0.f;
#pragma unroll
    for (int mi = 0; mi < 4; ++mi) {
#pragma unroll
      for (int rg = 0; rg < 4; ++rg) {
        int gm = m0 + rl + mi*16 + rg;
        if (gm < M) {
          float v = acc[mi][ni][rg] + bvv;
          if (epi == 4 || epi == 5) v = gelu_f(v);
          size_t ix = (size_t)gm*ldc + gn;
          if (epi <= 4) Cf[ix] = v;
          else { u16 h = f2bf(v); Ch[ix] = h; Cl[ix] = f2bf(v - bf2f(h)); }
        }
      }
    }
  }
}

// ---------- GEMM, pre-split bf16 A-pair x B-pair (3 MFMAs/tile: ~fp32 fidelity) ----------
__global__ __launch_bounds__(256) void k_gemm_bb(
    const u16* __restrict__ Ahg, const u16* __restrict__ Alg,
    const u16* __restrict__ Bth, const u16* __restrict__ Btl,
    const float* __restrict__ bias,
    float* __restrict__ Cf, u16* __restrict__ Ch, u16* __restrict__ Cl,
    int M, int K, int ldc, int epi)
{
  __shared__ __align__(16) u16 sAh[128*LS], sAl[128*LS], sBh[128*LS], sBl[128*LS];
  const int tid = threadIdx.x, lane = tid & 63;
  const int m0 = blockIdx.x*128, n0 = blockIdx.y*128;
  const int wm = (tid>>6)&1, wn = (tid>>7)&1;
  f32x4 acc[4][4] = {};
  for (int kt = 0; kt < K; kt += 32) {
    uint4 ra[2], rb[2], rc[2], rd[2];
#pragma unroll
    for (int r = 0; r < 2; ++r) {
      int c = r*256+tid, m = c>>2, q = c&3;
      int gm = m0+m; if (gm > M-1) gm = M-1;
      size_t ao = (size_t)gm*K + kt + q*8;
      ra[r] = *(const uint4*)(Ahg+ao);
      rb[r] = *(const uint4*)(Alg+ao);
      size_t bo = (size_t)(n0+m)*K + kt + q*8;
      rc[r] = *(const uint4*)(Bth+bo);
      rd[r] = *(const uint4*)(Btl+bo);
    }
    __syncthreads();
#pragma unroll
    for (int r = 0; r < 2; ++r) {
      int c = r*256+tid, m = c>>2, q = c&3;
      *(uint4*)(sAh + m*LS + q*8) = ra[r];
      *(uint4*)(sAl + m*LS + q*8) = rb[r];
      *(uint4*)(sBh + m*LS + q*8) = rc[r];
      *(uint4*)(sBl + m*LS + q*8) = rd[r];
    }
    __syncthreads();
    const int qq = lane>>4, ml = lane&15;
    bf16x8 fah[4], fal[4], fbh[4], fbl[4];
#pragma unroll
    for (int i = 0; i < 4; ++i) {
      fah[i] = *(const bf16x8*)(sAh + (wm*64+i*16+ml)*LS + qq*8);
      fal[i] = *(const bf16x8*)(sAl + (wm*64+i*16+ml)*LS + qq*8);
      fbh[i] = *(const bf16x8*)(sBh + (wn*64+i*16+ml)*LS + qq*8);
      fbl[i] = *(const bf16x8*)(sBl + (wn*64+i*16+ml)*LS + qq*8);
    }
#pragma unroll
    for (int mi = 0; mi < 4; ++mi)
#pragma unroll
      for (int ni = 0; ni < 4; ++ni) {
        acc[mi][ni] = __builtin_amdgcn_mfma_f32_16x16x32_bf16(fah[mi], fbl[ni], acc[mi][ni], 0, 0, 0);
        acc[mi][ni] = __builtin_amdgcn_mfma_f32_16x16x32_bf16(fal[mi], fbh[ni], acc[mi][ni], 0, 0, 0);
        acc[mi][ni] = __builtin_amdgcn_mfma_f32_16x16x32_bf16(fah[mi], fbh[ni], acc[mi][ni], 0, 0, 0);
      }
  }
  epi_std(acc, bias, Cf, Ch, Cl, M, ldc, epi, m0, n0, lane, wm, wn);
}

// ---------- GEMM, gathered pre-split A (feat row = [nodes[src]|nodes[snk]|eattr]), K=384 ----------
// epi==2: score mode — lrelu, dot with aA slice, block-reduce -> scores[row, head=blockIdx.y]
__global__ __launch_bounds__(256) void k_gemm_gbb(
    const u16* __restrict__ nh, const u16* __restrict__ nl,
    const u16* __restrict__ eh, const u16* __restrict__ el,
    const int* __restrict__ src, const int* __restrict__ snk,
    const u16* __restrict__ Bth, const u16* __restrict__ Btl,
    const float* __restrict__ bias,
    float* __restrict__ Cf, u16* __restrict__ Ch, u16* __restrict__ Cl,
    const float* __restrict__ aA, const float* __restrict__ aAb,
    float* __restrict__ scoresOut,
    int M, int ldc, int epi)
{
  __shared__ __align__(16) u16 sAh[128*LS], sAl[128*LS], sBh[128*LS], sBl[128*LS];
  const int tid = threadIdx.x, lane = tid & 63;
  const int m0 = blockIdx.x*128, n0 = blockIdx.y*128;
  const int wm = (tid>>6)&1, wn = (tid>>7)&1;
  const u16 *ph0[2], *ph1[2], *ph2[2], *pl0[2], *pl1[2], *pl2[2];
#pragma unroll
  for (int r = 0; r < 2; ++r) {
    int c = r*256+tid, m = c>>2;
    int gl = m0+m; if (gl > M-1) gl = M-1;
    int s = src[gl], k2 = snk[gl];
    ph0[r] = nh + (size_t)s*DD;  pl0[r] = nl + (size_t)s*DD;
    ph1[r] = nh + (size_t)k2*DD; pl1[r] = nl + (size_t)k2*DD;
    ph2[r] = eh + (size_t)gl*DD; pl2[r] = el + (size_t)gl*DD;
  }
  f32x4 acc[4][4] = {};
  for (int kt = 0; kt < CC; kt += 32) {
    uint4 ra[2], rb[2], rc[2], rd[2];
#pragma unroll
    for (int r = 0; r < 2; ++r) {
      int c = r*256+tid, m = c>>2, q = c&3;
      int col = kt + q*8;
      const u16* sh = (col < 128) ? ph0[r] : (col < 256) ? ph1[r] : ph2[r];
      const u16* sl = (col < 128) ? pl0[r] : (col < 256) ? pl1[r] : pl2[r];
      int cc = col & 127;
      ra[r] = *(const uint4*)(sh + cc);
      rb[r] = *(const uint4*)(sl + cc);
      size_t bo = (size_t)(n0+m)*CC + kt + q*8;
      rc[r] = *(const uint4*)(Bth+bo);
      rd[r] = *(const uint4*)(Btl+bo);
    }
    __syncthreads();
#pragma unroll
    for (int r = 0; r < 2; ++r) {
      int c = r*256+tid, m = c>>2, q = c&3;
      *(uint4*)(sAh + m*LS + q*8) = ra[r];
      *(uint4*)(sAl + m*LS + q*8) = rb[r];
      *(uint4*)(sBh + m*LS + q*8) = rc[r];
      *(uint4*)(sBl + m*LS + q*8) = rd[r];
    }
    __syncthreads();
    const int qq = lane>>4, ml = lane&15;
    bf16x8 fah[4], fal[4], fbh[4], fbl[4];
#pragma unroll
    for (int i = 0; i < 4; ++i) {
      fah[i] = *(const bf16x8*)(sAh + (wm*64+i*16+ml)*LS + qq*8);
      fal[i] = *(const bf16x8*)(sAl + (wm*64+i*16+ml)*LS + qq*8);
      fbh[i] = *(const bf16x8*)(sBh + (wn*64+i*16+ml)*LS + qq*8);
      fbl[i] = *(const bf16x8*)(sBl + (wn*64+i*16+ml)*LS + qq*8);
    }
#pragma unroll
    for (int mi = 0; mi < 4; ++mi)
#pragma unroll
      for (int ni = 0; ni < 4; ++ni) {
        acc[mi][ni] = __builtin_amdgcn_mfma_f32_16x16x32_bf16(fah[mi], fbl[ni], acc[mi][ni], 0, 0, 0);
        acc[mi][ni] = __builtin_amdgcn_mfma_f32_16x16x32_bf16(fal[mi], fbh[ni], acc[mi][ni], 0, 0, 0);
        acc[mi][ni] = __builtin_amdgcn_mfma_f32_16x16x32_bf16(fah[mi], fbh[ni], acc[mi][ni], 0, 0, 0);
      }
  }
  if (epi == 2) {
    // fused score reduction: scores[row, h] = sum_n lrelu(Z[row,n]+bias[n]) * aA[n] + aAb[h]
    const int cl_ = wn*64 + (lane & 15);
    float part[4][4] = {};
#pragma unroll
    for (int ni = 0; ni < 4; ++ni) {
      int gn = n0 + cl_ + ni*16;
      float bvv = bias[gn];
      float av = aA[gn];
#pragma unroll
      for (int mi = 0; mi < 4; ++mi)
#pragma unroll
        for (int rg = 0; rg < 4; ++rg) {
          float v = acc[mi][ni][rg] + bvv;
          v = (v > 0.f) ? v : 0.2f*v;
          part[mi][rg] += v*av;
        }
    }
#pragma unroll
    for (int mi = 0; mi < 4; ++mi)
#pragma unroll
      for (int rg = 0; rg < 4; ++rg) {
        float s = part[mi][rg];
        s += __shfl_xor(s, 1, 64); s += __shfl_xor(s, 2, 64);
        s += __shfl_xor(s, 4, 64); s += __shfl_xor(s, 8, 64);
        part[mi][rg] = s;
      }
    __syncthreads();                       // all frag reads done; reuse sAh as reduction buffer
    float* sred = (float*)sAh;             // [2][128]
    if ((lane & 15) == 0) {
#pragma unroll
      for (int mi = 0; mi < 4; ++mi)
#pragma unroll
        for (int rg = 0; rg < 4; ++rg)
          sred[wn*128 + wm*64 + mi*16 + (lane>>4)*4 + rg] = part[mi][rg];
    }
    __syncthreads();
    if (tid < 128) {
      int gm = m0 + tid;
      if (gm < M) scoresOut[(size_t)gm*4 + blockIdx.y] = sred[tid] + sred[128 + tid] + aAb[blockIdx.y];
    }
    return;
  }
  epi_std(acc, bias, Cf, Ch, Cl, M, ldc, epi, m0, n0, lane, wm, wn);
}

// ---------------- small kernels ----------------
__global__ void k_detect(const u16* __restrict__ d, int n, int* __restrict__ flag) {
  __shared__ int cnt;
  if (threadIdx.x == 0) cnt = 0;
  __syncthreads();
  int c = 0;
  for (int i = threadIdx.x; i < n; i += blockDim.x) {
    int e = (d[i] >> 7) & 0xff;
    if (e >= 0xC0) ++c;
  }
  atomicAdd(&cnt, c);
  __syncthreads();
  if (threadIdx.x == 0) *flag = (cnt > 16) ? 1 : 0;
}

struct ConvDesc { const void* src; float* dst; int n; };
struct ConvArgs { ConvDesc d[30]; };
__global__ void k_conv32(ConvArgs a, const int* __restrict__ flag) {
  ConvDesc de = a.d[blockIdx.y];
  int fp = *flag;
  for (int i = blockIdx.x*256 + threadIdx.x; i < de.n; i += gridDim.x*256)
    de.dst[i] = fp ? ((const float*)de.src)[i] : bf2f(((const u16*)de.src)[i]);
}

struct PackDesc { const float* src; u16* dh; u16* dl; int K, N, sk, sh; };
struct PackArgs { PackDesc d[20]; int n; };
__global__ void k_pack2(PackArgs a) {
  PackDesc de = a.d[blockIdx.y];
  int total = de.K * de.N;
  for (int i = blockIdx.x*256 + threadIdx.x; i < total; i += gridDim.x*256) {
    int k = i / de.N, n = i - k*de.N;
    float x = de.src[(size_t)k*de.sk + (n & 127) + (n >> 7)*de.sh];
    u16 h = f2bf(x);
    de.dh[(size_t)n*de.K + k] = h;
    de.dl[(size_t)n*de.K + k] = f2bf(x - bf2f(h));
  }
}

__global__ void k_init_nodes(const int* __restrict__ seq, const float* __restrict__ emb,
                             u16* __restrict__ nh, u16* __restrict__ nl) {
  int i = blockIdx.x*256 + threadIdx.x;
  if (i >= NN*DD) return;
  int n = i >> 7, d = i & 127;
  float v = emb[seq[n]*DD + d];
  u16 h = f2bf(v); nh[i] = h; nl[i] = f2bf(v - bf2f(h));
}

__global__ void k_rbf_s(const float* __restrict__ dist, const float* __restrict__ W,
                        const float* __restrict__ b, u16* __restrict__ eh, u16* __restrict__ el) {
  int e = blockIdx.x, t = threadIdx.x;
  float d = dist[e];
  float acc = b[t];
#pragma unroll
  for (int k = 0; k < 16; ++k) {
    float mu = 2.f + (20.f/15.f)*(float)k;
    float z = (d - mu)*0.8f;
    acc += (expf(-z*z) + 1e-8f)*W[k*DD + t];
  }
  u16 h = f2bf(acc);
  eh[(size_t)e*DD + t] = h; el[(size_t)e*DD + t] = f2bf(acc - bf2f(h));
}

__global__ void k_hist(const int* __restrict__ snk, int* __restrict__ deg) {
  int e = blockIdx.x*256 + threadIdx.x;
  if (e < EE) atomicAdd(&deg[snk[e]], 1);
}
__global__ void k_scan(const int* __restrict__ deg, int* __restrict__ ptr, int* __restrict__ cursor, int n) {
  __shared__ int buf[1024];
  __shared__ int carry_s;
  int tid = threadIdx.x;
  if (tid == 0) carry_s = 0;
  __syncthreads();
  for (int base = 0; base < n; base += 1024) {
    int i = base + tid;
    int v = (i < n) ? deg[i] : 0;
    buf[tid] = v;
    __syncthreads();
    for (int off = 1; off < 1024; off <<= 1) {
      int t = (tid >= off) ? buf[tid - off] : 0;
      __syncthreads();
      buf[tid] += t;
      __syncthreads();
    }
    int excl = buf[tid] - v;
    int carry = carry_s;
    if (i < n) { ptr[i] = carry + excl; cursor[i] = carry + excl; }
    __syncthreads();
    if (tid == 1023) carry_s = carry + buf[1023];
    __syncthreads();
  }
  if (tid == 0) ptr[n] = carry_s;
}
__global__ void k_scatter(const int* __restrict__ snk, int* __restrict__ cursor, int* __restrict__ csr) {
  int e = blockIdx.x*256 + threadIdx.x;
  if (e < EE) { int p = atomicAdd(&cursor[snk[e]], 1); csr[p] = e; }
}

__global__ void k_softmax(const float* __restrict__ scores, const int* __restrict__ ptr,
                          const int* __restrict__ csr, float* __restrict__ att, int nnodes) {
  int node = blockIdx.x*4 + (threadIdx.x >> 6);
  if (node >= nnodes) return;
  int lane = threadIdx.x & 63;
  int h = lane >> 4, j = lane & 15;
  int b = ptr[node], e = ptr[node+1];
  float mx = -1e30f;
  for (int i = b + j; i < e; i += 16) mx = fmaxf(mx, scores[(size_t)csr[i]*4 + h]);
  mx = fmaxf(mx, __shfl_xor(mx, 1, 64)); mx = fmaxf(mx, __shfl_xor(mx, 2, 64));
  mx = fmaxf(mx, __shfl_xor(mx, 4, 64)); mx = fmaxf(mx, __shfl_xor(mx, 8, 64));
  float s = 0.f;
  for (int i = b + j; i < e; i += 16) s += expf(scores[(size_t)csr[i]*4 + h] - mx);
  s += __shfl_xor(s, 1, 64); s += __shfl_xor(s, 2, 64);
  s += __shfl_xor(s, 4, 64); s += __shfl_xor(s, 8, 64);
  float norm = s + (float)(e - b)*1e-12f;
  float inv = (e > b) ? 1.f/norm : 0.f;
  for (int i = b + j; i < e; i += 16) {
    int ed = csr[i];
    att[(size_t)ed*4 + h] = expf(scores[(size_t)ed*4 + h] - mx)*inv;
  }
}

__global__ void k_aggregate(const float* __restrict__ att,
                            const u16* __restrict__ nuh, const u16* __restrict__ nul,
                            const int* __restrict__ ptr, const int* __restrict__ csr,
                            u16* __restrict__ agh, u16* __restrict__ agl) {
  int node = blockIdx.x; int d = threadIdx.x;  // 128 threads
  int b = ptr[node], e = ptr[node+1];
  float a0=0.f, a1=0.f, a2=0.f, a3=0.f;
  for (int i = b; i < e; ++i) {
    int ed = csr[i];
    float4 a = *(const float4*)(att + (size_t)ed*4);
    float v = bf2f(nuh[(size_t)ed*DD + d]) + bf2f(nul[(size_t)ed*DD + d]);
    a0 += a.x*v; a1 += a.y*v; a2 += a.z*v; a3 += a.w*v;
  }
  size_t o = (size_t)node*HDIM + d;
  float vs[4] = {a0,a1,a2,a3};
#pragma unroll
  for (int k = 0; k < 4; ++k) {
    u16 h = f2bf(vs[k]); agh[o + k*128] = h; agl[o + k*128] = f2bf(vs[k] - bf2f(h));
  }
}

// mode 0: x = (nh+nl) + upd ; mode 1: x = dense_f + upd. Writes node pair.
__global__ void k_ln_node(u16* __restrict__ nh, u16* __restrict__ nl,
                          const float* __restrict__ upd, const float* __restrict__ dense_f,
                          const float* __restrict__ g, const float* __restrict__ b,
                          int mode, int rows) {
  int r = blockIdx.x*4 + (threadIdx.x >> 6);
  if (r >= rows) return;
  int lane = threadIdx.x & 63;
  size_t o = (size_t)r*DD;
  float x0, x1;
  if (mode == 0) { x0 = bf2f(nh[o+lane]) + bf2f(nl[o+lane]); x1 = bf2f(nh[o+lane+64]) + bf2f(nl[o+lane+64]); }
  else           { x0 = dense_f[o+lane]; x1 = dense_f[o+lane+64]; }
  x0 += upd[o+lane]; x1 += upd[o+lane+64];
  float s = x0 + x1;
#pragma unroll
  for (int m = 1; m < 64; m <<= 1) s += __shfl_xor(s, m, 64);
  float mean = s * (1.f/128.f);
  float d0 = x0 - mean, d1 = x1 - mean;
  float vv = d0*d0 + d1*d1;
#pragma unroll
  for (int m = 1; m < 64; m <<= 1) vv += __shfl_xor(vv, m, 64);
  float inv = rsqrtf(vv*(1.f/128.f) + 1e-5f);
  float y0 = d0*inv*g[lane]    + b[lane];
  float y1 = d1*inv*g[lane+64] + b[lane+64];
  u16 h0 = f2bf(y0), h1 = f2bf(y1);
  nh[o+lane] = h0;    nl[o+lane] = f2bf(y0 - bf2f(h0));
  nh[o+lane+64] = h1; nl[o+lane+64] = f2bf(y1 - bf2f(h1));
}

__global__ void k_ln_edge(u16* __restrict__ eh, u16* __restrict__ el,
                          const u16* __restrict__ uh, const u16* __restrict__ ul,
                          const float* __restrict__ g, const float* __restrict__ b, int rows) {
  int r = blockIdx.x*4 + (threadIdx.x >> 6);
  if (r >= rows) return;
  int lane = threadIdx.x & 63;
  size_t o = (size_t)r*DD;
  float x0 = bf2f(eh[o+lane])    + bf2f(el[o+lane])    + bf2f(uh[o+lane])    + bf2f(ul[o+lane]);
  float x1 = bf2f(eh[o+lane+64]) + bf2f(el[o+lane+64]) + bf2f(uh[o+lane+64]) + bf2f(ul[o+lane+64]);
  float s = x0 + x1;
#pragma unroll
  for (int m = 1; m < 64; m <<= 1) s += __shfl_xor(s, m, 64);
  float mean = s * (1.f/128.f);
  float d0 = x0 - mean, d1 = x1 - mean;
  float vv = d0*d0 + d1*d1;
#pragma unroll
  for (int m = 1; m < 64; m <<= 1) vv += __shfl_xor(vv, m, 64);
  float inv = rsqrtf(vv*(1.f/128.f) + 1e-5f);
  float y0 = d0*inv*g[lane]    + b[lane];
  float y1 = d1*inv*g[lane+64] + b[lane+64];
  u16 h0 = f2bf(y0), h1 = f2bf(y1);
  eh[o+lane] = h0;    el[o+lane] = f2bf(y0 - bf2f(h0));
  eh[o+lane+64] = h1; el[o+lane+64] = f2bf(y1 - bf2f(h1));
}

__global__ void k_finalize(const u16* __restrict__ nh, const u16* __restrict__ nl,
                           const u16* __restrict__ eh, const u16* __restrict__ el,
                           void* __restrict__ out, const int* __restrict__ flag) {
  int i = blockIdx.x*256 + threadIdx.x;
  if (i >= OUT_TOTAL) return;
  int fp = *flag;
  float v;
  if (i < OUT_NODES) v = bf2f(nh[i]) + bf2f(nl[i]);
  else { int j = i - OUT_NODES; v = bf2f(eh[j]) + bf2f(el[j]); }
  if (fp) ((float*)out)[i] = v; else ((u16*)out)[i] = f2bf(v);
}

extern "C" void kernel_launch(void* const* d_in, const int* in_sizes, int n_in,
                              void* d_out, int out_size, void* d_ws, size_t ws_size,
                              hipStream_t stream)
{
  const int* seq_idx = (const int*)d_in[0];
  const int* esrc = (const int*)d_in[1];
  const int* esnk = ((const int*)d_in[1]) + EE;

  char* wsp = (char*)d_ws;
  size_t off = 0;
  auto carve = [&](size_t bytes)->char* {
    char* p = wsp + off; off += (bytes + 255) & ~(size_t)255; return p;
  };
  // Total ~232 MB (R2's 245.7 worked; R3's 308.6 faulted)
  int* flag       = (int*)carve(256);
  float* upd_f    = (float*)carve((size_t)NN*DD*4);
  float* dense_f  = (float*)carve((size_t)NN*DD*4);
  u16* nodes_h    = (u16*)carve((size_t)NN*DD*2);
  u16* nodes_l    = (u16*)carve((size_t)NN*DD*2);
  u16* eattr_h    = (u16*)carve((size_t)EE*DD*2);
  u16* eattr_l    = (u16*)carve((size_t)EE*DD*2);
  u16* Ba_h       = (u16*)carve((size_t)EE*DD*2);
  u16* Ba_l       = (u16*)carve((size_t)EE*DD*2);
  u16* Bb_h       = (u16*)carve((size_t)EE*DD*2);
  u16* Bb_l       = (u16*)carve((size_t)EE*DD*2);
  float* scores   = (float*)carve((size_t)EE*4*4);
  float* att      = (float*)carve((size_t)EE*4*4);
  u16* agg_h      = (u16*)carve((size_t)NN*HDIM*2);
  u16* agg_l      = (u16*)carve((size_t)NN*HDIM*2);
  u16* dh_h       = (u16*)carve((size_t)NN*HDIM*2);
  u16* dh_l       = (u16*)carve((size_t)NN*HDIM*2);
  u16* wpk_h      = (u16*)carve(557056ULL*2*2);
  u16* wpk_l      = (u16*)carve(557056ULL*2*2);
  int* deg        = (int*)carve((size_t)NN*4);
  int* ptrb       = (int*)carve((size_t)(NN+1)*4);
  int* cursor     = (int*)carve((size_t)NN*4);
  int* csr        = (int*)carve((size_t)EE*4);

  static const int FCNT[32] = {0,0,120000,2688,2048,128,393216,1024,1024,8,
    98304,256,32768,256,32768,256, 131072,1024,131072,256,
    98304,256,32768,256,32768,256, 131072,256, 256,256,256,256};
  float* cf[32];
  for (int i = 2; i < 32; ++i) cf[i] = (float*)carve((size_t)FCNT[i]*4);
  (void)ws_size; (void)in_sizes; (void)n_in; (void)out_size;

  k_detect<<<1, 1024, 0, stream>>>((const u16*)d_in[2], 120000, flag);
  ConvArgs ca;
  for (int i = 2; i < 32; ++i) { ca.d[i-2].src = d_in[i]; ca.d[i-2].dst = cf[i]; ca.d[i-2].n = FCNT[i]; }
  hipLaunchKernelGGL(k_conv32, dim3(96, 30), dim3(256), 0, stream, ca, flag);

  const size_t PW_L = 557056;
  PackArgs pa; int nd = 0;
  for (int l = 0; l < 2; ++l) {
    size_t base = l*PW_L;
    auto add = [&](const float* s, size_t doff, int K, int N, int sk, int sh){
      pa.d[nd].src = s; pa.d[nd].dh = wpk_h + doff; pa.d[nd].dl = wpk_l + doff;
      pa.d[nd].K = K; pa.d[nd].N = N; pa.d[nd].sk = sk; pa.d[nd].sh = sh; ++nd; };
    add(cf[6]  + l*196608, base + 0,      384, 512, 128, 49152);  // aW^T (n = h*128+d)
    add(cf[10] + l*49152,  base + 196608, 384, 128, 128, 0);      // nmlp_W1
    add(cf[12] + l*16384,  base + 245760, 128, 128, 128, 0);      // nmlp_W2
    add(cf[14] + l*16384,  base + 262144, 128, 128, 128, 0);      // nmlp_W3
    add(cf[26] + l*65536,  base + 278528, 512, 128, 128, 0);      // aggr_W
    add(cf[16] + l*65536,  base + 344064, 128, 512, 512, 128);    // dmlp_W1
    add(cf[18] + l*65536,  base + 409600, 512, 128, 128, 0);      // dmlp_W2
    add(cf[20] + l*49152,  base + 475136, 384, 128, 128, 0);      // emlp_W1
    add(cf[22] + l*16384,  base + 524288, 128, 128, 128, 0);      // emlp_W2
    add(cf[24] + l*16384,  base + 540672, 128, 128, 128, 0);      // emlp_W3
  }
  pa.n = nd;
  hipLaunchKernelGGL(k_pack2, dim3(768, nd), dim3(256), 0, stream, pa);

  k_init_nodes<<<(NN*DD + 255)/256, 256, 0, stream>>>(seq_idx, cf[3], nodes_h, nodes_l);
  k_rbf_s<<<EE, 128, 0, stream>>>(cf[2], cf[4], cf[5], eattr_h, eattr_l);

  hipMemsetAsync(deg, 0, (size_t)NN*4, stream);
  k_hist<<<(EE + 255)/256, 256, 0, stream>>>(esnk, deg);
  k_scan<<<1, 1024, 0, stream>>>(deg, ptrb, cursor, NN);
  k_scatter<<<(EE + 255)/256, 256, 0, stream>>>(esnk, cursor, csr);

  for (int l = 0; l < 2; ++l) {
    const u16* bh = wpk_h + l*PW_L; const u16* bl = wpk_l + l*PW_L;
    // attention scores: full-E gathered GEMM with fused lrelu+aA reduction -> scores
    k_gemm_gbb<<<dim3(938, 4), 256, 0, stream>>>(nodes_h, nodes_l, eattr_h, eattr_l, esrc, esnk,
        bh + 0, bl + 0, cf[7] + l*512, nullptr, nullptr, nullptr,
        cf[8] + l*512, cf[9] + l*4, scores, EE, 512, 2);
    // node-update MLP on edges (pairs end-to-end; nupd -> Bb pair)
    k_gemm_gbb<<<dim3(938, 1), 256, 0, stream>>>(nodes_h, nodes_l, eattr_h, eattr_l, esrc, esnk,
        bh + 196608, bl + 196608, cf[11] + l*128, nullptr, Bb_h, Bb_l,
        nullptr, nullptr, nullptr, EE, 128, 5);
    k_gemm_bb<<<dim3(938, 1), 256, 0, stream>>>(Bb_h, Bb_l, bh + 245760, bl + 245760,
        cf[13] + l*128, nullptr, Ba_h, Ba_l, EE, 128, 128, 5);
    k_gemm_bb<<<dim3(938, 1), 256, 0, stream>>>(Ba_h, Ba_l, bh + 262144, bl + 262144,
        cf[15] + l*128, nullptr, Bb_h, Bb_l, EE, 128, 128, 6);
    // scatter softmax + aggregation
    k_softmax<<<(NN + 3)/4, 256, 0, stream>>>(scores, ptrb, csr, att, NN);
    k_aggregate<<<NN, 128, 0, stream>>>(att, Bb_h, Bb_l, ptrb, csr, agg_h, agg_l);
    // upd = agg @ aggr_W + b (fp32 out)
    k_gemm_bb<<<dim3(47, 1), 256, 0, stream>>>(agg_h, agg_l, bh + 278528, bl + 278528,
        cf[27] + l*128, upd_f, nullptr, nullptr, NN, 512, 128, 3);
    k_ln_node<<<(NN + 3)/4, 256, 0, stream>>>(nodes_h, nodes_l, upd_f, (const float*)nullptr,
        cf[28] + l*128, cf[29] + l*128, 0, NN);
    // dense MLP
    k_gemm_bb<<<dim3(47, 4), 256, 0, stream>>>(nodes_h, nodes_l, bh + 344064, bl + 344064,
        cf[17] + l*512, nullptr, dh_h, dh_l, NN, 128, 512, 5);
    k_gemm_bb<<<dim3(47, 1), 256, 0, stream>>>(dh_h, dh_l, bh + 409600, bl + 409600,
        cf[19] + l*128, dense_f, nullptr, nullptr, NN, 512, 128, 3);
    k_ln_node<<<(NN + 3)/4, 256, 0, stream>>>(nodes_h, nodes_l, upd_f, dense_f,
        cf[28] + l*128, cf[29] + l*128, 1, NN);
    // edge MLP (eu -> Ba pair)
    k_gemm_gbb<<<dim3(938, 1), 256, 0, stream>>>(nodes_h, nodes_l, eattr_h, eattr_l, esrc, esnk,
        bh + 475136, bl + 475136, cf[21] + l*128, nullptr, Ba_h, Ba_l,
        nullptr, nullptr, nullptr, EE, 128, 5);
    k_gemm_bb<<<dim3(938, 1), 256, 0, stream>>>(Ba_h, Ba_l, bh + 524288, bl + 524288,
        cf[23] + l*128, nullptr, Bb_h, Bb_l, EE, 128, 128, 5);
    k_gemm_bb<<<dim3(938, 1), 256, 0, stream>>>(Bb_h, Bb_l, bh + 540672, bl + 540672,
        cf[25] + l*128, nullptr, Ba_h, Ba_l, EE, 128, 128, 6);
    k_ln_edge<<<(EE + 3)/4, 256, 0, stream>>>(eattr_h, eattr_l, Ba_h, Ba_l,
        cf[30] + l*128, cf[31] + l*128, EE);
  }
  k_finalize<<<(OUT_TOTAL + 255)/256, 256, 0, stream>>>(nodes_h, nodes_l, eattr_h, eattr_l, d_out, flag);
}